// Round 7
// baseline (69.877 us; speedup 1.0000x reference)
//
#include <hip/hip_runtime.h>

// Quantum state-vector simulation: out[b] = Re( M[b>>2] @ input[b] ).
// Qubit q <-> amp bit (9-q). Entangler == Gray permute: state'[x^(x>>1)] = state[x].
//
// R7: as R6 (128 blocks x 256 thr, 4 amps/lane, fused LDS exchange for bits 8,9
// + Gray permute, 9 barriers) but the six cross-lane gates (amp bits 2-7) are
// fused into THREE two-qubit lane exchanges: per pair (M,M+1), 3 independent
// shfl_xor (masks 1,2,3 << M) in ONE latency round + 4-term coefficient-fused
// complex accumulate. Cuts dependent shuffle rounds per layer 6 -> 3.
// OUTPUT: out_size==131072 -> f32 real part (verified); 262144 -> bf16 fallback.

#define DIM 1024
#define NQ 10
#define NLAYERS 8
#define NGATES 80

__device__ __forceinline__ unsigned short f2bf(float f) {
    unsigned int u = __float_as_uint(f);
    unsigned int r = u + 0x7FFFu + ((u >> 16) & 1u);
    return (unsigned short)(r >> 16);
}

__device__ __forceinline__ float2 cmul(float2 a, float2 b) {
    return make_float2(a.x * b.x - a.y * b.y, a.x * b.y + a.y * b.x);
}
__device__ __forceinline__ float2 cfma(float2 c, float2 x, float2 acc) {
    acc.x = fmaf(c.x, x.x, fmaf(-c.y, x.y, acc.x));
    acc.y = fmaf(c.x, x.y, fmaf(c.y, x.x, acc.y));
    return acc;
}
// c0*x0 + c1*x1
__device__ __forceinline__ float2 cmadd2(float2 c0, float2 x0, float2 c1, float2 x1) {
    float re = c0.x * x0.x - c0.y * x0.y + c1.x * x1.x - c1.y * x1.y;
    float im = c0.x * x0.y + c0.y * x0.x + c1.x * x1.y + c1.y * x1.x;
    return make_float2(re, im);
}

struct G4 { float2 m11, m12, m21, m22; };

template <int K>  // amp bit K in {0,1}: register-local pairs within a[4]
__device__ __forceinline__ void local_gate(float2 (&a)[4], const G4& g) {
#pragma unroll
    for (int p = 0; p < 2; ++p) {
        const int i0 = ((p >> K) << (K + 1)) | (p & ((1 << K) - 1));
        const int i1 = i0 | (1 << K);
        const float2 a0 = a[i0], a1 = a[i1];
        a[i0] = cmadd2(g.m11, a0, g.m12, a1);
        a[i1] = cmadd2(g.m21, a0, g.m22, a1);
    }
}

// Fused two-qubit cross-lane gate: A acts on amp bit M+2 (lane bit M),
// B acts on amp bit M+3 (lane bit M+1). new(h,l) = sum B[h][h'] A[l][l'] old(h',l').
template <int M>
__device__ __forceinline__ void cross_pair(float2 (&a)[4], int lane,
                                           const G4& A, const G4& B) {
    const bool blo = (lane >> M) & 1;
    const bool bhi = (lane >> (M + 1)) & 1;
    const float2 Ad = blo ? A.m22 : A.m11;   // A[l][l]
    const float2 Ax = blo ? A.m21 : A.m12;   // A[l][~l]
    const float2 Bd = bhi ? B.m22 : B.m11;   // B[h][h]
    const float2 Bx = bhi ? B.m21 : B.m12;   // B[h][~h]
    const float2 c_s  = cmul(Bd, Ad);
    const float2 c_lo = cmul(Bd, Ax);
    const float2 c_hi = cmul(Bx, Ad);
    const float2 c_b  = cmul(Bx, Ax);
#pragma unroll
    for (int r = 0; r < 4; ++r) {
        float2 o1, o2, o3;
        o1.x = __shfl_xor(a[r].x, 1 << M, 64);  o1.y = __shfl_xor(a[r].y, 1 << M, 64);
        o2.x = __shfl_xor(a[r].x, 2 << M, 64);  o2.y = __shfl_xor(a[r].y, 2 << M, 64);
        o3.x = __shfl_xor(a[r].x, 3 << M, 64);  o3.y = __shfl_xor(a[r].y, 3 << M, 64);
        float2 acc = cmul(c_s, a[r]);
        acc = cfma(c_lo, o1, acc);
        acc = cfma(c_hi, o2, acc);
        acc = cfma(c_b,  o3, acc);
        a[r] = acc;
    }
}

__global__ __launch_bounds__(256) void
UnitaryR3Ansatz_18846316495450_kernel(const float* __restrict__ inp,     // [128][1024] f32
                                      const float* __restrict__ params,  // [32][8][10][3] f32
                                      void* __restrict__ outp,
                                      int out_size)
{
    __shared__ float4 gates[NGATES][2];   // [0]=(m11,m12), [1]=(m21,m22) re/im packed
    __shared__ float4 stA[DIM / 2];
    __shared__ float4 stB[DIM / 2];

    const int b = blockIdx.x;        // vector 0..127
    const int c = b >> 2;            // params copy
    const int tid = threadIdx.x;     // 0..255 == amp bits 2-9
    const int lane = tid & 63;       // amp bits 2-7

    if (tid < NGATES) {
        const float* p = params + c * (NGATES * 3) + tid * 3;
        const float omega = p[0], theta = p[1], phi = p[2];
        float sh, ch;  sincosf(0.5f * theta, &sh, &ch);
        float sa, ca;  sincosf(0.5f * (phi + omega), &sa, &ca);
        float sb, cb;  sincosf(0.5f * (phi - omega), &sb, &cb);
        gates[tid][0] = make_float4(ca * ch, -sa * ch, -cb * sh, -sb * sh);  // m11,m12
        gates[tid][1] = make_float4(cb * sh, -sb * sh, ca * ch, sa * ch);    // m21,m22
    }

    float2 a[4];
    {
        const float4 v = ((const float4*)(inp + b * DIM))[tid];
        a[0] = make_float2(v.x, 0.f);
        a[1] = make_float2(v.y, 0.f);
        a[2] = make_float2(v.z, 0.f);
        a[3] = make_float2(v.w, 0.f);
    }

    // exchange constants: y = tid*4 + r (output amp); z = invgray10(y)
    const int xb = tid << 2;
    int zb = xb;
    zb ^= zb >> 1; zb ^= zb >> 2; zb ^= zb >> 4; zb ^= zb >> 8;
    const int  zmid = zb & 0xFC;
    const bool z8 = (zb >> 8) & 1;
    const bool z9 = (zb >> 9) & 1;
    const bool s0 = zb & 1;
    const bool s1 = zb & 2;

    __syncthreads();

    float4* buf = stA;
    for (int l = 0; l < NLAYERS; ++l) {
        const float4* gl = &gates[l * NQ][0];
#define LOADG(q) G4{ make_float2(gl[2*(q)].x,   gl[2*(q)].y),   \
                     make_float2(gl[2*(q)].z,   gl[2*(q)].w),   \
                     make_float2(gl[2*(q)+1].x, gl[2*(q)+1].y), \
                     make_float2(gl[2*(q)+1].z, gl[2*(q)+1].w) }
        { const G4 g = LOADG(9); local_gate<0>(a, g); }              // bit 0
        { const G4 g = LOADG(8); local_gate<1>(a, g); }              // bit 1
        { const G4 gA = LOADG(7), gB = LOADG(6); cross_pair<0>(a, lane, gA, gB); }  // bits 2,3
        { const G4 gA = LOADG(5), gB = LOADG(4); cross_pair<2>(a, lane, gA, gB); }  // bits 4,5
        { const G4 gA = LOADG(3), gB = LOADG(2); cross_pair<4>(a, lane, gA, gB); }  // bits 6,7

        // ---- LDS exchange: gates on bits 8,9 (qubits 1,0) + Gray permute ----
        buf[tid * 2]     = make_float4(a[0].x, a[0].y, a[1].x, a[1].y);
        buf[tid * 2 + 1] = make_float4(a[2].x, a[2].y, a[3].x, a[3].y);
        __syncthreads();

        const G4 g1 = LOADG(1);   // qubit 1 -> bit 8
        const float2 h0 = z8 ? g1.m21 : g1.m11;
        const float2 h1 = z8 ? g1.m22 : g1.m12;
        const G4 g0g = LOADG(0);  // qubit 0 -> bit 9
        const float2 g0r = z9 ? g0g.m21 : g0g.m11;
        const float2 g1r = z9 ? g0g.m22 : g0g.m12;
#undef LOADG

        float2 v0[4], v1[4];
        {   // b9 = 0
            const float4 p0 = buf[(zmid) >> 1],          p1 = buf[((zmid) >> 1) + 1];
            const float4 q0 = buf[(0x100 | zmid) >> 1],  q1 = buf[((0x100 | zmid) >> 1) + 1];
            v0[0] = cmadd2(h0, make_float2(p0.x, p0.y), h1, make_float2(q0.x, q0.y));
            v0[1] = cmadd2(h0, make_float2(p0.z, p0.w), h1, make_float2(q0.z, q0.w));
            v0[2] = cmadd2(h0, make_float2(p1.x, p1.y), h1, make_float2(q1.x, q1.y));
            v0[3] = cmadd2(h0, make_float2(p1.z, p1.w), h1, make_float2(q1.z, q1.w));
        }
        {   // b9 = 1
            const float4 p0 = buf[(0x200 | zmid) >> 1],  p1 = buf[((0x200 | zmid) >> 1) + 1];
            const float4 q0 = buf[(0x300 | zmid) >> 1],  q1 = buf[((0x300 | zmid) >> 1) + 1];
            v1[0] = cmadd2(h0, make_float2(p0.x, p0.y), h1, make_float2(q0.x, q0.y));
            v1[1] = cmadd2(h0, make_float2(p0.z, p0.w), h1, make_float2(q0.z, q0.w));
            v1[2] = cmadd2(h0, make_float2(p1.x, p1.y), h1, make_float2(q1.x, q1.y));
            v1[3] = cmadd2(h0, make_float2(p1.z, p1.w), h1, make_float2(q1.z, q1.w));
        }
        float2 u[4];
#pragma unroll
        for (int j = 0; j < 4; ++j) u[j] = cmadd2(g0r, v0[j], g1r, v1[j]);

        const float2 w0 = s0 ? u[1] : u[0];
        const float2 w1 = s0 ? u[0] : u[1];
        const float2 w2 = s0 ? u[3] : u[2];
        const float2 w3 = s0 ? u[2] : u[3];
        a[0] = s1 ? w2 : w0;
        a[1] = s1 ? w3 : w1;
        a[2] = s1 ? w1 : w3;
        a[3] = s1 ? w0 : w2;

        buf = (l & 1) ? stA : stB;
    }

    if (out_size >= 2 * DIM * 128) {
        ushort2* o2 = (ushort2*)outp + (size_t)b * DIM + tid * 4;
#pragma unroll
        for (int i = 0; i < 4; ++i) {
            ushort2 v; v.x = f2bf(a[i].x); v.y = f2bf(a[i].y);
            o2[i] = v;
        }
    } else {
        ((float4*)((float*)outp + (size_t)b * DIM))[tid] =
            make_float4(a[0].x, a[1].x, a[2].x, a[3].x);
    }
}

extern "C" void kernel_launch(void* const* d_in, const int* in_sizes, int n_in,
                              void* d_out, int out_size, void* d_ws, size_t ws_size,
                              hipStream_t stream) {
    const float* inp    = (const float*)d_in[0];   // 131072 f32
    const float* params = (const float*)d_in[1];   // 7680 f32
    (void)in_sizes; (void)n_in; (void)d_ws; (void)ws_size;
    UnitaryR3Ansatz_18846316495450_kernel<<<128, 256, 0, stream>>>(inp, params, d_out, out_size);
}